// Round 9
// baseline (230.585 us; speedup 1.0000x reference)
//
#include <hip/hip_runtime.h>
#include <hip/hip_cooperative_groups.h>
#include <cstddef>

#define B_    4
#define CIN_  256
#define COUT_ 256
#define H_    64
#define W_    64
#define KK_   9
#define G_    4
#define PW    80          // padded row width  (pad 8 each side)
#define PH    80          // padded rows
#define PADO  8           // pad offset

typedef short bf16x8 __attribute__((ext_vector_type(8)));
typedef float f32x4  __attribute__((ext_vector_type(4)));
typedef __attribute__((address_space(1))) const unsigned int* gptr_t;
typedef __attribute__((address_space(3))) unsigned int*       lptr_t;

__device__ __forceinline__ unsigned short f2bf(float v) {
    unsigned int u = __float_as_uint(v);
    u += 0x7fffu + ((u >> 16) & 1u);
    return (unsigned short)(u >> 16);
}
__device__ __forceinline__ float f_lo(unsigned int u) { return __uint_as_float(u << 16); }
__device__ __forceinline__ float f_hi(unsigned int u) { return __uint_as_float(u & 0xffff0000u); }

// ONE cooperative kernel: 256 blocks x 512 threads, 1 block/CU (160 KB LDS).
// PHASE A (prep): each block transposes the exact (b,h) x-row it consumes in
// phase B (same XCD -> row stays in local L2); 64 blocks zero border rows;
// wb repack spread over all blocks. Then device-fence + grid.sync (cross-XCD
// visibility: release wbl2 / acquire inv -- Guideline 16).
// PHASE B: round-7's measured-best dcn body verbatim (tap-pair K=128,
// 3-phase LDS, counted vmcnt, fused relu epilogue).
__global__ __launch_bounds__(512, 2) void dcn_fused(
    const float* __restrict__ x, const float* __restrict__ y,
    const float* __restrict__ w_off, const float* __restrict__ w_def,
    unsigned short* __restrict__ xTp, unsigned short* __restrict__ wb,
    float* __restrict__ out)
{
    __shared__ unsigned short s_W[2][2][16384];   // [buf][tap-half] 128 KB
    __shared__ unsigned short s_S[2][2][4096];    // [buf][tap-half]  32 KB

    const int tid = threadIdx.x;
    const int bid = blockIdx.x;                 // 256 blocks = 1/CU
    const int xcd = bid & 7;
    const int b   = xcd >> 1;
    const int h   = (xcd & 1) * 32 + (bid >> 3);

    // ================= PHASE A: prep =================
    {
        // ---- wb repack: 36*16384 shorts over 131072 threads ----
        #pragma unroll
        for (int r = 0; r < 5; ++r) {
            int idx = r * 131072 + bid * 512 + tid;
            if (idx < 589824) {
                int e = idx & 7, pos = (idx >> 3) & 7, o = (idx >> 6) & 255;
                int t = idx >> 14;
                int g = t / 9, kk = t - g * 9;
                int j = pos ^ (o & 7);
                int c = g * 64 + j * 8 + e;
                wb[idx] = f2bf(w_def[(o * 256 + c) * 9 + kk]);
            }
        }
        // ---- border rows: 64 blocks zero one 80x256 row each ----
        if ((bid & 1) == 0 && (bid >> 3) < 16) {
            int rr = bid >> 3;
            int yp = rr < 8 ? rr : 64 + rr;       // 0..7 or 72..79
            unsigned short* dz = xTp + ((size_t)b * PH + yp) * (PW * 256);
            #pragma unroll
            for (int k = 0; k < 5; ++k)           // 2560 uint4
                *(uint4*)(dz + (size_t)(k * 512 + tid) * 8) = make_uint4(0,0,0,0);
        }
        // ---- own row transpose: x[b][:, h, :] -> xTp[b][h+8][xp][c] ----
        unsigned short* scr = &s_W[0][0][0];      // [64 w][pitch 264] = 33 KB
        #pragma unroll
        for (int k = 0; k < 32; ++k) {            // 16384 floats
            int i = k * 512 + tid; int c = i >> 6, w = i & 63;
            scr[w * 264 + c] = f2bf(x[((size_t)(b * 256 + c) * 64 + h) * 64 + w]);
        }
        __syncthreads();
        unsigned short* dr = xTp + ((size_t)b * PH + h + 8) * (PW * 256);
        #pragma unroll
        for (int k = 0; k < 5; ++k) {             // 80 xp x 32 chunks = 2560 uint4
            int j = k * 512 + tid; int xp = j >> 5, ch = (j & 31) * 8;
            uint4 v = make_uint4(0, 0, 0, 0);
            if (xp >= 8 && xp < 72) v = *(const uint4*)(scr + (xp - 8) * 264 + ch);
            *(uint4*)(dr + (size_t)xp * 256 + ch) = v;
        }
    }
    __threadfence();                              // release: drain + L2 writeback
    cooperative_groups::this_grid().sync();
    __threadfence();                              // acquire: invalidate stale lines
    __syncthreads();

    // ================= PHASE B: r7 dcn body =================
    const int sp = tid >> 3;          // pixel 0..63
    const int c8 = tid & 7;           // 8-ch chunk 0..7

    const float yv0 = y[((b * 2 + 0) * H_ + h) * W_ + sp];
    const float yv1 = y[((b * 2 + 1) * H_ + h) * W_ + sp];
    const float spf = (float)(sp - 1 + PADO);
    const float hpf = (float)(h  - 1 + PADO);

    const int lane = tid & 63, wave = tid >> 6;
    const int pg  = wave & 1, oh = wave >> 1;       // oh 0..3
    const int l15 = lane & 15, kq = lane >> 4, sw = l15 & 7;

    f32x4 acc[8];   // [nt][mt] : 2 px-subtiles x 4 out-subtiles
    #pragma unroll
    for (int i = 0; i < 8; ++i) acc[i] = (f32x4){0.f, 0.f, 0.f, 0.f};

    const unsigned short* xb = xTp + (size_t)b * (PH * PW * 256) + c8 * 8;

    float wgt[2][4];
    uint4 gA[2], gB[2], gC[2], gD[2];

#define ISSUE_ONE(t, P) do {                                                   \
    const int t_ = (t);                                                        \
    const int g_ = t_ / 9, kk_ = t_ - g_ * 9;                                  \
    const float4 co = *(const float4*)(w_off + t_ * 4);                        \
    const float dy = fmaf(yv0, co.x, yv1 * co.y);                              \
    const float dx = fmaf(yv0, co.z, yv1 * co.w);                              \
    const float yc = hpf + (float)(kk_ / 3) + dy;                              \
    const float xc = spf + (float)(kk_ % 3) + dx;                              \
    const float yf = floorf(yc), xf = floorf(xc);                              \
    const float wy = yc - yf, wx = xc - xf;                                    \
    const int   yi = (int)yf, xi = (int)xf;     /* padded coords, >= 0 */      \
    const float omy = 1.f - wy, omx = 1.f - wx;                                \
    wgt[P][0] = omy * omx; wgt[P][1] = omy * wx;                               \
    wgt[P][2] = wy * omx;  wgt[P][3] = wy * wx;                                \
    const unsigned short* p0 = xb + (yi * PW + xi) * 256 + g_ * 64;            \
    const unsigned short* p1 = p0 + PW * 256;                                  \
    gA[P] = *(const uint4*)(p0);        gB[P] = *(const uint4*)(p0 + 256);     \
    gC[P] = *(const uint4*)(p1);        gD[P] = *(const uint4*)(p1 + 256);     \
} while (0)

#define STAGE_W2(t, buf) do {                                                  \
    const unsigned short* src = wb + (size_t)(t) * 32768;                      \
    _Pragma("unroll")                                                          \
    for (int j = 0; j < 8; ++j) {                                              \
        const int off = (j * 512 + tid) * 8;                                   \
        __builtin_amdgcn_global_load_lds((gptr_t)(src + off),                  \
                                         (lptr_t)(&s_W[buf][0][0] + off),      \
                                         16, 0, 0);                            \
    }                                                                          \
} while (0)

#define WRITE_ONE(P, SB) do {                                                  \
    const unsigned int av[4] = {gA[P].x, gA[P].y, gA[P].z, gA[P].w};           \
    const unsigned int bv[4] = {gB[P].x, gB[P].y, gB[P].z, gB[P].w};           \
    const unsigned int cv[4] = {gC[P].x, gC[P].y, gC[P].z, gC[P].w};           \
    const unsigned int dv[4] = {gD[P].x, gD[P].y, gD[P].z, gD[P].w};           \
    unsigned int res[4];                                                       \
    _Pragma("unroll")                                                          \
    for (int q = 0; q < 4; ++q) {                                              \
        float rl = wgt[P][0] * f_lo(av[q]);                                    \
        rl = fmaf(wgt[P][1], f_lo(bv[q]), rl);                                 \
        rl = fmaf(wgt[P][2], f_lo(cv[q]), rl);                                 \
        rl = fmaf(wgt[P][3], f_lo(dv[q]), rl);                                 \
        float rh = wgt[P][0] * f_hi(av[q]);                                    \
        rh = fmaf(wgt[P][1], f_hi(bv[q]), rh);                                 \
        rh = fmaf(wgt[P][2], f_hi(cv[q]), rh);                                 \
        rh = fmaf(wgt[P][3], f_hi(dv[q]), rh);                                 \
        res[q] = __builtin_amdgcn_perm(__float_as_uint(rh),                    \
                                       __float_as_uint(rl), 0x07060302u);      \
    }                                                                          \
    *(uint4*)(&s_S[SB][P][0] + sp * 64 + ((c8 ^ (sp & 7)) * 8)) =              \
        make_uint4(res[0], res[1], res[2], res[3]);                            \
} while (0)

#define MFMA_TAP(WB, HF, SB) do {                                              \
    bf16x8 bf[2][2], af[2][4];                                                 \
    _Pragma("unroll")                                                          \
    for (int kh = 0; kh < 2; ++kh) {                                           \
        const int pos = ((kh * 4 + kq) ^ sw) * 8;                              \
        _Pragma("unroll")                                                      \
        for (int nt = 0; nt < 2; ++nt)                                         \
            bf[kh][nt] = *(const bf16x8*)(&s_S[SB][HF][0] +                    \
                              (pg * 32 + nt * 16 + l15) * 64 + pos);           \
        _Pragma("unroll")                                                      \
        for (int mt = 0; mt < 4; ++mt)                                         \
            af[kh][mt] = *(const bf16x8*)(&s_W[WB][HF][0] +                    \
                              (oh * 64 + mt * 16 + l15) * 64 + pos);           \
    }                                                                          \
    __builtin_amdgcn_s_setprio(1);                                             \
    _Pragma("unroll")                                                          \
    for (int kh = 0; kh < 2; ++kh)                                             \
        _Pragma("unroll")                                                      \
        for (int nt = 0; nt < 2; ++nt)                                         \
            _Pragma("unroll")                                                  \
            for (int mt = 0; mt < 4; ++mt)                                     \
                acc[nt * 4 + mt] = __builtin_amdgcn_mfma_f32_16x16x32_bf16(    \
                    af[kh][mt], bf[kh][nt], acc[nt * 4 + mt], 0, 0, 0);        \
    __builtin_amdgcn_s_setprio(0);                                             \
} while (0)

#define STEP(s_, P, DO_PF) do {                                                \
    if (DO_PF) { ISSUE_ONE(2 * (s_) + 2, 0); ISSUE_ONE(2 * (s_) + 3, 1); }     \
    __builtin_amdgcn_sched_barrier(0);                                         \
    if (DO_PF) STAGE_W2((s_) + 1, P ^ 1);                                      \
    __builtin_amdgcn_sched_barrier(0);                                         \
    MFMA_TAP(P, 0, P);                                                         \
    MFMA_TAP(P, 1, P);                                                         \
    __builtin_amdgcn_sched_barrier(0);                                         \
    if (DO_PF) { WRITE_ONE(0, P ^ 1); WRITE_ONE(1, P ^ 1); }                   \
    __builtin_amdgcn_sched_barrier(0);                                         \
    asm volatile("s_waitcnt vmcnt(0) lgkmcnt(0)" ::: "memory");                \
    __builtin_amdgcn_sched_barrier(0);                                         \
    __builtin_amdgcn_s_barrier();                                              \
    __builtin_amdgcn_sched_barrier(0);                                         \
} while (0)

    // ---- prologue: gather+stage pair 0, write S[0], drain, barrier ----
    ISSUE_ONE(0, 0);
    ISSUE_ONE(1, 1);
    __builtin_amdgcn_sched_barrier(0);
    STAGE_W2(0, 0);
    __builtin_amdgcn_sched_barrier(0);
    WRITE_ONE(0, 0);                 // auto vmcnt(8): retires gathers
    WRITE_ONE(1, 0);
    __builtin_amdgcn_sched_barrier(0);
    asm volatile("s_waitcnt vmcnt(0) lgkmcnt(0)" ::: "memory");
    __builtin_amdgcn_sched_barrier(0);
    __builtin_amdgcn_s_barrier();
    __builtin_amdgcn_sched_barrier(0);

    // ---- main loop: pairs 0..15 (static buf indices), then 16, then 17 ----
    for (int sb = 0; sb < 16; sb += 2) {
        STEP(sb + 0, 0, 1);
        STEP(sb + 1, 1, 1);
    }
    STEP(16, 0, 1);                   // prefetches pair 17 -> buf1 / S[1]
    MFMA_TAP(1, 0, 1);                // pair 17, no barrier before epilogue
    MFMA_TAP(1, 1, 1);

    // ---- epilogue: fused relu, direct final store. C/D: col->px, row->o ----
    #pragma unroll
    for (int nt = 0; nt < 2; ++nt) {
        const int px = pg * 32 + nt * 16 + l15;
        #pragma unroll
        for (int mt = 0; mt < 4; ++mt) {
            const int obase = oh * 64 + mt * 16 + kq * 4;
            #pragma unroll
            for (int rr = 0; rr < 4; ++rr) {
                out[(((size_t)b * COUT_ + obase + rr) * H_ + h) * W_ + px] =
                    fmaxf(acc[nt * 4 + mt][rr], 0.f);
            }
        }
    }
#undef ISSUE_ONE
#undef STAGE_W2
#undef WRITE_ONE
#undef MFMA_TAP
#undef STEP
}

extern "C" void kernel_launch(void* const* d_in, const int* in_sizes, int n_in,
                              void* d_out, int out_size, void* d_ws, size_t ws_size,
                              hipStream_t stream) {
    const float* x     = (const float*)d_in[0];
    const float* y     = (const float*)d_in[1];
    const float* w_off = (const float*)d_in[2];
    const float* w_def = (const float*)d_in[3];
    float* out = (float*)d_out;

    unsigned short* xTp = (unsigned short*)d_ws;            // 4*80*80*256*2B = 13.1 MB
    unsigned short* wb  = (unsigned short*)d_ws + (size_t)B_ * PH * PW * 256;  // 1.18 MB

    void* kargs[] = { (void*)&x, (void*)&y, (void*)&w_off, (void*)&w_def,
                      (void*)&xTp, (void*)&wb, (void*)&out };
    hipLaunchCooperativeKernel((const void*)dcn_fused, dim3(256), dim3(512),
                               kargs, 0, stream);
}

// Round 10
// 118.355 us; speedup vs baseline: 1.9482x; 1.9482x over previous
//
#include <hip/hip_runtime.h>
#include <cstddef>

#define B_    4
#define CIN_  256
#define COUT_ 256
#define H_    64
#define W_    64
#define KK_   9
#define G_    4
#define PW    80          // padded row width  (pad 8 each side)
#define PH    80          // padded rows
#define PADO  8           // pad offset

typedef short bf16x8 __attribute__((ext_vector_type(8)));
typedef float f32x4  __attribute__((ext_vector_type(4)));
typedef __attribute__((address_space(1))) const unsigned int* gptr_t;
typedef __attribute__((address_space(3))) unsigned int*       lptr_t;

__device__ __forceinline__ unsigned short f2bf(float v) {
    unsigned int u = __float_as_uint(v);
    u += 0x7fffu + ((u >> 16) & 1u);
    return (unsigned short)(u >> 16);
}
__device__ __forceinline__ float f_lo(unsigned int u) { return __uint_as_float(u << 16); }
__device__ __forceinline__ float f_hi(unsigned int u) { return __uint_as_float(u & 0xffff0000u); }

// Merged prep (r7 verbatim):
//   blocks [0,512):    xTp interior rows (x-borders zeroed inline)
//   blocks [512,576):  xTp border rows zero-fill
//   blocks [576,2880): wb weight repack (36 tiles, pos-swizzled)
__global__ __launch_bounds__(256) void prep_kernel(const float* __restrict__ x,
                                                   unsigned short* __restrict__ xTp,
                                                   const float* __restrict__ w,
                                                   unsigned short* __restrict__ wb) {
    const int tid = threadIdx.x;
    if (blockIdx.x < 512) {
        __shared__ unsigned short s[128][66];
        const int bh    = blockIdx.x >> 1;
        const int chalf = blockIdx.x & 1;
        const int b     = bh >> 6, h = bh & 63;
        const size_t src_base = ((size_t)b * CIN_ + chalf * 128) * (H_ * W_) + h * W_;
        #pragma unroll 4
        for (int k = 0; k < 32; ++k) {
            int i = k * 256 + tid;
            int c = i >> 6, ww = i & 63;
            s[c][ww] = f2bf(x[src_base + (size_t)c * (H_ * W_) + ww]);
        }
        __syncthreads();
        const size_t dst_row = ((size_t)b * PH + (h + PADO)) * PW;
        #pragma unroll 4
        for (int k = 0; k < 20; ++k) {              // 80 w' x 64 ch-pairs
            int j  = k * 256 + tid;
            int c2 = (j & 63) * 2, wp = j >> 6;     // wp in [0,80)
            unsigned int v = 0;
            if (wp >= PADO && wp < PADO + W_) {
                int ww = wp - PADO;
                v = (unsigned int)s[c2][ww] | ((unsigned int)s[c2 + 1][ww] << 16);
            }
            *(unsigned int*)(xTp + (dst_row + wp) * 256 + chalf * 128 + c2) = v;
        }
    } else if (blockIdx.x < 576) {
        const int bidx = blockIdx.x - 512;          // [0,64)
        const int b = bidx >> 4, rr = bidx & 15;
        const int yp = (rr < PADO) ? rr : (PH - 16 + rr);   // 0..7 or 72..79
        unsigned short* dst = xTp + ((size_t)b * PH + yp) * PW * 256;
        #pragma unroll
        for (int k = 0; k < 10; ++k) {              // 80*256 shorts = 2560 x 16B
            *(uint4*)(dst + (size_t)(k * 256 + tid) * 8) = make_uint4(0, 0, 0, 0);
        }
    } else {
        int idx = (blockIdx.x - 576) * 256 + tid;   // 36*16384 exactly
        int e   = idx & 7;
        int pos = (idx >> 3) & 7;
        int o   = (idx >> 6) & 255;
        int t   = idx >> 14;                        // g*9 + kk
        int g   = t / 9, kk = t - g * 9;
        int j   = pos ^ (o & 7);
        int c   = g * 64 + j * 8 + e;
        wb[idx] = f2bf(w[(o * CIN_ + c) * KK_ + kk]);
    }
}

// Main kernel: r7's tap-pair structure (measured best, 45.7 us) with ALL
// sched_barrier(0) pins and raw-asm waitcnts REMOVED (m141 lesson: pinning
// defeats the compiler scheduler). Step body interleaves the two independent
// chains (ds_read->MFMA and gather->bilinear->ds_write) in source order;
// the compiler inserts precise per-register vmcnt/lgkmcnt waits and
// co-schedules VALU with MFMA. One __syncthreads per pair-step.
__global__ __launch_bounds__(512, 2) void dcn_kernel(
    const unsigned short* __restrict__ xTp, const float* __restrict__ y,
    const float* __restrict__ w_off, const unsigned short* __restrict__ wb,
    float* __restrict__ out)
{
    __shared__ unsigned short s_W[2][2][16384];   // [buf][tap-half][256o*64c] 128 KB
    __shared__ unsigned short s_S[2][2][4096];    // [buf][tap-half][64px*64c]  32 KB

    const int tid = threadIdx.x;
    const int bid = blockIdx.x;                 // 256 blocks = 1/CU
    const int xcd = bid & 7;
    const int b   = xcd >> 1;
    const int h   = (xcd & 1) * 32 + (bid >> 3);

    // sampling mapping: 8 threads per pixel, 8 channels (16B) each
    const int sp = tid >> 3;          // pixel 0..63
    const int c8 = tid & 7;           // 8-ch chunk 0..7

    const float yv0 = y[((b * 2 + 0) * H_ + h) * W_ + sp];
    const float yv1 = y[((b * 2 + 1) * H_ + h) * W_ + sp];
    const float spf = (float)(sp - 1 + PADO);       // x base (pre-padded)
    const float hpf = (float)(h  - 1 + PADO);       // y base (pre-padded)

    // mfma mapping: 8 waves, wave = 64 outs (oh) x 32 px (pg)
    const int lane = tid & 63, wave = tid >> 6;
    const int pg  = wave & 1, oh = wave >> 1;       // oh 0..3
    const int l15 = lane & 15, kq = lane >> 4, sw = l15 & 7;

    f32x4 acc[8];   // [nt][mt] : 2 px-subtiles x 4 out-subtiles
    #pragma unroll
    for (int i = 0; i < 8; ++i) acc[i] = (f32x4){0.f, 0.f, 0.f, 0.f};

    const unsigned short* xb = xTp + (size_t)b * (PH * PW * 256) + c8 * 8;

    // two tap slots in flight (all indices compile-time -- rule #20)
    float wgt[2][4];
    uint4 gA[2], gB[2], gC[2], gD[2];

#define ISSUE_ONE(t, P) do {                                                   \
    const int t_ = (t);                                                        \
    const int g_ = t_ / 9, kk_ = t_ - g_ * 9;                                  \
    const float4 co = *(const float4*)(w_off + t_ * 4);                        \
    const float dy = fmaf(yv0, co.x, yv1 * co.y);                              \
    const float dx = fmaf(yv0, co.z, yv1 * co.w);                              \
    const float yc = hpf + (float)(kk_ / 3) + dy;                              \
    const float xc = spf + (float)(kk_ % 3) + dx;                              \
    const float yf = floorf(yc), xf = floorf(xc);                              \
    const float wy = yc - yf, wx = xc - xf;                                    \
    const int   yi = (int)yf, xi = (int)xf;     /* padded coords, >= 0 */      \
    const float omy = 1.f - wy, omx = 1.f - wx;                                \
    wgt[P][0] = omy * omx; wgt[P][1] = omy * wx;                               \
    wgt[P][2] = wy * omx;  wgt[P][3] = wy * wx;                                \
    const unsigned short* p0 = xb + (yi * PW + xi) * 256 + g_ * 64;            \
    const unsigned short* p1 = p0 + PW * 256;                                  \
    gA[P] = *(const uint4*)(p0);        gB[P] = *(const uint4*)(p0 + 256);     \
    gC[P] = *(const uint4*)(p1);        gD[P] = *(const uint4*)(p1 + 256);     \
} while (0)

// stage one PAIR (2 consecutive wb tiles = 64 KB) into s_W[buf]
#define STAGE_W2(t, buf) do {                                                  \
    const unsigned short* src = wb + (size_t)(t) * 32768;                      \
    _Pragma("unroll")                                                          \
    for (int j = 0; j < 8; ++j) {                                              \
        const int off = (j * 512 + tid) * 8;                                   \
        __builtin_amdgcn_global_load_lds((gptr_t)(src + off),                  \
                                         (lptr_t)(&s_W[buf][0][0] + off),      \
                                         16, 0, 0);                            \
    }                                                                          \
} while (0)

#define WRITE_ONE(P, SB) do {                                                  \
    const unsigned int av[4] = {gA[P].x, gA[P].y, gA[P].z, gA[P].w};           \
    const unsigned int bv[4] = {gB[P].x, gB[P].y, gB[P].z, gB[P].w};           \
    const unsigned int cv[4] = {gC[P].x, gC[P].y, gC[P].z, gC[P].w};           \
    const unsigned int dv[4] = {gD[P].x, gD[P].y, gD[P].z, gD[P].w};           \
    unsigned int res[4];                                                       \
    _Pragma("unroll")                                                          \
    for (int q = 0; q < 4; ++q) {                                              \
        float rl = wgt[P][0] * f_lo(av[q]);                                    \
        rl = fmaf(wgt[P][1], f_lo(bv[q]), rl);                                 \
        rl = fmaf(wgt[P][2], f_lo(cv[q]), rl);                                 \
        rl = fmaf(wgt[P][3], f_lo(dv[q]), rl);                                 \
        float rh = wgt[P][0] * f_hi(av[q]);                                    \
        rh = fmaf(wgt[P][1], f_hi(bv[q]), rh);                                 \
        rh = fmaf(wgt[P][2], f_hi(cv[q]), rh);                                 \
        rh = fmaf(wgt[P][3], f_hi(dv[q]), rh);                                 \
        res[q] = __builtin_amdgcn_perm(__float_as_uint(rh),                    \
                                       __float_as_uint(rl), 0x07060302u);      \
    }                                                                          \
    *(uint4*)(&s_S[SB][P][0] + sp * 64 + ((c8 ^ (sp & 7)) * 8)) =              \
        make_uint4(res[0], res[1], res[2], res[3]);                            \
} while (0)

// one K=64 MFMA block: W buf WB, tap-half HF, S buf SB (r2-proven layout)
#define MFMA_TAP(WB, HF, SB) do {                                              \
    bf16x8 bf[2][2], af[2][4];                                                 \
    _Pragma("unroll")                                                          \
    for (int kh = 0; kh < 2; ++kh) {                                           \
        const int pos = ((kh * 4 + kq) ^ sw) * 8;                              \
        _Pragma("unroll")                                                      \
        for (int nt = 0; nt < 2; ++nt)                                         \
            bf[kh][nt] = *(const bf16x8*)(&s_S[SB][HF][0] +                    \
                              (pg * 32 + nt * 16 + l15) * 64 + pos);           \
        _Pragma("unroll")                                                      \
        for (int mt = 0; mt < 4; ++mt)                                         \
            af[kh][mt] = *(const bf16x8*)(&s_W[WB][HF][0] +                    \
                              (oh * 64 + mt * 16 + l15) * 64 + pos);           \
    }                                                                          \
    __builtin_amdgcn_s_setprio(1);                                             \
    _Pragma("unroll")                                                          \
    for (int kh = 0; kh < 2; ++kh)                                             \
        _Pragma("unroll")                                                      \
        for (int nt = 0; nt < 2; ++nt)                                         \
            _Pragma("unroll")                                                  \
            for (int mt = 0; mt < 4; ++mt)                                     \
                acc[nt * 4 + mt] = __builtin_amdgcn_mfma_f32_16x16x32_bf16(    \
                    af[kh][mt], bf[kh][nt], acc[nt * 4 + mt], 0, 0, 0);        \
    __builtin_amdgcn_s_setprio(0);                                             \
} while (0)

// Pair-step s (P = s&1). NO scheduling pins: the gather->bilinear->ds_write
// chain (for pair s+1) and the ds_read->MFMA chain (pair s) are independent;
// the compiler interleaves them and inserts exact counted waits. The single
// __syncthreads drains DMA+ds_writes and flips the double buffer.
#define STEP(s_, P, DO_PF) do {                                                \
    if (DO_PF) { ISSUE_ONE(2 * (s_) + 2, 0); ISSUE_ONE(2 * (s_) + 3, 1); }     \
    if (DO_PF) STAGE_W2((s_) + 1, P ^ 1);                                      \
    MFMA_TAP(P, 0, P);                                                         \
    if (DO_PF) WRITE_ONE(0, P ^ 1);                                            \
    MFMA_TAP(P, 1, P);                                                         \
    if (DO_PF) WRITE_ONE(1, P ^ 1);                                            \
    __syncthreads();                                                           \
} while (0)

    // ---- prologue: gather+stage pair 0, write S[0], sync ----
    ISSUE_ONE(0, 0);
    ISSUE_ONE(1, 1);
    STAGE_W2(0, 0);
    WRITE_ONE(0, 0);
    WRITE_ONE(1, 0);
    __syncthreads();

    // ---- main loop: pairs 0..15 (static buf indices), then 16, then 17 ----
    for (int sb = 0; sb < 16; sb += 2) {
        STEP(sb + 0, 0, 1);
        STEP(sb + 1, 1, 1);
    }
    STEP(16, 0, 1);                   // prefetches pair 17 -> buf1 / S[1]
    MFMA_TAP(1, 0, 1);                // pair 17, no barrier before epilogue
    MFMA_TAP(1, 1, 1);

    // ---- epilogue: fused relu, direct final store. C/D: col->px, row->o ----
    #pragma unroll
    for (int nt = 0; nt < 2; ++nt) {
        const int px = pg * 32 + nt * 16 + l15;
        #pragma unroll
        for (int mt = 0; mt < 4; ++mt) {
            const int obase = oh * 64 + mt * 16 + kq * 4;
            #pragma unroll
            for (int rr = 0; rr < 4; ++rr) {
                out[(((size_t)b * COUT_ + obase + rr) * H_ + h) * W_ + px] =
                    fmaxf(acc[nt * 4 + mt][rr], 0.f);
            }
        }
    }
#undef ISSUE_ONE
#undef STAGE_W2
#undef WRITE_ONE
#undef MFMA_TAP
#undef STEP
}

extern "C" void kernel_launch(void* const* d_in, const int* in_sizes, int n_in,
                              void* d_out, int out_size, void* d_ws, size_t ws_size,
                              hipStream_t stream) {
    const float* x     = (const float*)d_in[0];
    const float* y     = (const float*)d_in[1];
    const float* w_off = (const float*)d_in[2];
    const float* w_def = (const float*)d_in[3];
    float* out = (float*)d_out;

    unsigned short* xTp = (unsigned short*)d_ws;            // 4*80*80*256*2B = 13.1 MB
    unsigned short* wb  = (unsigned short*)d_ws + (size_t)B_ * PH * PW * 256;  // 1.18 MB

    prep_kernel<<<2880, 256, 0, stream>>>(x, xTp, w_def, wb);
    dcn_kernel<<<256, 512, 0, stream>>>(xTp, y, w_off, wb, out);
}